// Round 12
// baseline (98.079 us; speedup 1.0000x reference)
//
#include <hip/hip_runtime.h>

// Per-element MLP 1->32->(32x32)x9->1, leaky relu, v_mfma_f32_16x16x32_f16.
// R17 = R14 (41.8us steady, measured) with ONE change: MFMA issued via
// inline asm with "v"-class constraints, pinning A/B/C/D to arch VGPRs.
// Why: R14/R16 counters show VALU-issue ~16us/SIMD vs ~6.7us of source
// VALU -> emitted stream is ~2.4x inflated. VGPR_Count=92 is BELOW the
// kernel's live state (f 48 + accs 64 + io 12 + misc >= 130) -> the
// allocator put accs (+likely f) in AGPRs; on gfx950 VALU can't touch
// AGPRs, so every acc read is a v_accvgpr_read and every f/bias write a
// v_accvgpr_write (~70+ extra VALU/layer = the 2.4x + part of the 44%
// idle). Pinning to "v" deletes that traffic. Hazards: accs are read >=8
// MFMAs (~40cyc) after issue; MFMA reads f written ~40 insts earlier --
// both >> CDNA wait-state needs; lgkm deps flow through asm constraints.
// R16 lesson recorded: layers are serially dependent (MFMA(l+1) consumes
// epi(l)) -> unroll can't overlap cross-layer; it only bloated (46.4us).
// Confirmation signal: VGPR_Count 92 -> ~140-160, VALUBusy 39 -> ~26-30%.
#define NLAYERS 9
#define HID 32
#define SLOPE 0.01f

typedef _Float16 v2h __attribute__((ext_vector_type(2)));
typedef _Float16 v8h __attribute__((ext_vector_type(8)));
typedef float v4f __attribute__((ext_vector_type(4)));

#define NCHAIN 6

union U8 { v8h v; v2h p[4]; };          // B-operand fragment (8 f16 = 4 VGPRs)

__device__ __forceinline__ v2h pk_cvt(float a, float b) {
    return __builtin_bit_cast(v2h, __builtin_amdgcn_cvt_pkrtz(a, b));
}
__device__ __forceinline__ v2h leaky2(v2h t, v2h s) {
    return __builtin_elementwise_max(t, t * s);
}
// MFMA pinned to arch VGPRs ("v" class): no AGPR allocation -> no
// v_accvgpr_read/write traffic on the acc<->VALU path. "=&v" early-clobber
// keeps D off A/B/C (C = shared bias, must not be clobbered).
__device__ __forceinline__ v4f mfma_v(v8h a, v8h b, v4f c) {
    v4f d;
    asm("v_mfma_f32_16x16x32_f16 %0, %1, %2, %3"
        : "=&v"(d) : "v"(a), "v"(b), "v"(c));
    return d;
}
// k-slot (group g = lane>>4, elem j) -> logical hidden unit; derived from the
// verified 16x16 C/D layout so epilogue pk pairs feed the next B directly
// (validated numerically in R10/R14).
__device__ __forceinline__ int umap(int g, int j) {
    return 4 * g + (j & 3) + 16 * (j >> 2);
}

__global__ __launch_bounds__(256, 2) void mlp_mfma_kernel(
    const float* __restrict__ x,
    const float* __restrict__ W_in,   // [1,32]
    const float* __restrict__ b_in,   // [32]
    const float* __restrict__ W_hid,  // [9,32,32]  W[l][k_in][n_out]
    const float* __restrict__ b_hid,  // [9,32]
    const float* __restrict__ W_out,  // [32,1]
    const float* __restrict__ b_out,  // [1]
    float* __restrict__ out, int N)
{
    // A-operand fragments, pre-permuted: lane ln=(i | g<<4) of tile t reads
    // 16B contiguous = W[umap(g,j)][16t+i], j=0..7. 64x16B = conflict-free.
    __shared__ __align__(16) _Float16 wA_sh[NLAYERS][2][64][8];  // 18 KiB
    // f32 bias in 16x16 C layout: tile t, entry 4g+r <- b_hid[16t+4g+r]
    __shared__ __align__(64) float bc_sh[NLAYERS][2][16];        // 1.1 KiB

    const int tid = threadIdx.x;
    for (int t = tid; t < NLAYERS * 2 * 64; t += blockDim.x) {
        int l = t >> 7, r = t & 127, tt = (r >> 6) & 1, ln = r & 63;
        int i = ln & 15, gg = ln >> 4;
        const float* Wl = W_hid + l * HID * HID;
        v8h w;
#pragma unroll
        for (int j = 0; j < 8; ++j)
            w[j] = (_Float16)Wl[umap(gg, j) * HID + 16 * tt + i];
        *(v8h*)&wA_sh[l][tt][ln][0] = w;
    }
    for (int t = tid; t < NLAYERS * HID; t += blockDim.x)
        ((float*)bc_sh)[t] = b_hid[t];   // flat layout matches b_hid exactly
    __syncthreads();

    const int lane = tid & 63;
    const int g    = lane >> 4;     // k-group / C-row group
    const int col  = lane & 15;     // batch column within 16-wide half

    // ---- register-resident io-layer fragments (12 VGPRs) ----
    v2h win2[4], bin2[4], wout2[4];
#pragma unroll
    for (int jj = 0; jj < 4; ++jj) {
        int u0 = umap(g, 2 * jj), u1 = umap(g, 2 * jj + 1);  // u1 == u0+1
        win2[jj]  = v2h{(_Float16)W_in[u0],  (_Float16)W_in[u1]};
        bin2[jj]  = v2h{(_Float16)b_in[u0],  (_Float16)b_in[u1]};
        wout2[jj] = v2h{(_Float16)W_out[u0], (_Float16)W_out[u1]};
    }
    const float bo = b_out[0];
    const v2h slope2 = v2h{(_Float16)SLOPE, (_Float16)SLOPE};

    const int nwaves = (gridDim.x * blockDim.x) >> 6;
    const int wid    = (blockIdx.x * blockDim.x + tid) >> 6;
    const int niter  = (N + NCHAIN * 32 - 1) / (NCHAIN * 32);

    // ---- x prefetch for first iteration, packed f16 (2 cols/lane/chain) ----
    v2h xc2[NCHAIN];
#pragma unroll
    for (int c = 0; c < NCHAIN; ++c) xc2[c] = v2h{(_Float16)0.f, (_Float16)0.f};
    if (wid < niter) {
#pragma unroll
        for (int c = 0; c < NCHAIN; ++c) {
            int i0 = wid * (NCHAIN * 32) + c * 32 + col;
            int i1 = i0 + 16;
            float a = (i0 < N) ? x[i0] : 0.0f;
            float b = (i1 < N) ? x[i1] : 0.0f;
            xc2[c] = pk_cvt(a, b);
        }
    }

    for (int it = wid; it < niter; it += nwaves) {
        // prefetch next iteration's x (hides HBM latency under compute)
        v2h xn2[NCHAIN];
#pragma unroll
        for (int c = 0; c < NCHAIN; ++c) xn2[c] = v2h{(_Float16)0.f, (_Float16)0.f};
        {
            int nit = it + nwaves;
            if (nit < niter) {
#pragma unroll
                for (int c = 0; c < NCHAIN; ++c) {
                    int i0 = nit * (NCHAIN * 32) + c * 32 + col;
                    int i1 = i0 + 16;
                    float a = (i0 < N) ? x[i0] : 0.0f;
                    float b = (i1 < N) ? x[i1] : 0.0f;
                    xn2[c] = pk_cvt(a, b);
                }
            }
        }

        // ---- input layer: build B fragments for all chains/halves ----
        U8 f[NCHAIN][2];
#pragma unroll
        for (int c = 0; c < NCHAIN; ++c)
#pragma unroll
            for (int nh = 0; nh < 2; ++nh) {
                _Float16 xh = xc2[c][nh];
                v2h x2 = v2h{xh, xh};
#pragma unroll
                for (int jj = 0; jj < 4; ++jj)
                    f[c][nh].p[jj] = leaky2(x2 * win2[jj] + bin2[jj], slope2);
            }

        // ---- 9 hidden layers: rolled loop (R9 fix); weights/bias rotated;
        // 3 acc-groups STAGGERED so MFMA issue of group n+1 covers the
        // acc-read latency of group n. All MFMA state in arch VGPRs.
        v8h wA0 = *(const v8h*)&wA_sh[0][0][lane][0];
        v8h wA1 = *(const v8h*)&wA_sh[0][1][lane][0];
        v4f bc0 = *(const v4f*)&bc_sh[0][0][4 * g];
        v4f bc1 = *(const v4f*)&bc_sh[0][1][4 * g];
#pragma unroll 1
        for (int l = 0; l < NLAYERS; ++l) {
            const int lnx = (l + 1 < NLAYERS) ? l + 1 : l;
            v8h wA0n = *(const v8h*)&wA_sh[lnx][0][lane][0];
            v8h wA1n = *(const v8h*)&wA_sh[lnx][1][lane][0];
            v4f bc0n = *(const v4f*)&bc_sh[lnx][0][4 * g];
            v4f bc1n = *(const v4f*)&bc_sh[lnx][1][4 * g];

            v4f A0[2][4], A1[2][4], A2[2][4];
            // MFMA group 0 (chains 0,1)
#pragma unroll
            for (int q = 0; q < 2; ++q) {
                A0[q][0] = mfma_v(wA0, f[q][0].v, bc0);
                A0[q][1] = mfma_v(wA0, f[q][1].v, bc0);
                A0[q][2] = mfma_v(wA1, f[q][0].v, bc1);
                A0[q][3] = mfma_v(wA1, f[q][1].v, bc1);
            }
            // MFMA group 1 (chains 2,3)
#pragma unroll
            for (int q = 0; q < 2; ++q) {
                A1[q][0] = mfma_v(wA0, f[2 + q][0].v, bc0);
                A1[q][1] = mfma_v(wA0, f[2 + q][1].v, bc0);
                A1[q][2] = mfma_v(wA1, f[2 + q][0].v, bc1);
                A1[q][3] = mfma_v(wA1, f[2 + q][1].v, bc1);
            }
            // epi group 0 (covered by group 1's MFMA latency)
#pragma unroll
            for (int q = 0; q < 2; ++q) {
                f[q][0].p[0] = leaky2(pk_cvt(A0[q][0][0], A0[q][0][1]), slope2);
                f[q][0].p[1] = leaky2(pk_cvt(A0[q][0][2], A0[q][0][3]), slope2);
                f[q][0].p[2] = leaky2(pk_cvt(A0[q][2][0], A0[q][2][1]), slope2);
                f[q][0].p[3] = leaky2(pk_cvt(A0[q][2][2], A0[q][2][3]), slope2);
                f[q][1].p[0] = leaky2(pk_cvt(A0[q][1][0], A0[q][1][1]), slope2);
                f[q][1].p[1] = leaky2(pk_cvt(A0[q][1][2], A0[q][1][3]), slope2);
                f[q][1].p[2] = leaky2(pk_cvt(A0[q][3][0], A0[q][3][1]), slope2);
                f[q][1].p[3] = leaky2(pk_cvt(A0[q][3][2], A0[q][3][3]), slope2);
            }
            // MFMA group 2 (chains 4,5)
#pragma unroll
            for (int q = 0; q < 2; ++q) {
                A2[q][0] = mfma_v(wA0, f[4 + q][0].v, bc0);
                A2[q][1] = mfma_v(wA0, f[4 + q][1].v, bc0);
                A2[q][2] = mfma_v(wA1, f[4 + q][0].v, bc1);
                A2[q][3] = mfma_v(wA1, f[4 + q][1].v, bc1);
            }
            // epi group 1 (covered by group 2's MFMA latency)
#pragma unroll
            for (int q = 0; q < 2; ++q) {
                f[2 + q][0].p[0] = leaky2(pk_cvt(A1[q][0][0], A1[q][0][1]), slope2);
                f[2 + q][0].p[1] = leaky2(pk_cvt(A1[q][0][2], A1[q][0][3]), slope2);
                f[2 + q][0].p[2] = leaky2(pk_cvt(A1[q][2][0], A1[q][2][1]), slope2);
                f[2 + q][0].p[3] = leaky2(pk_cvt(A1[q][2][2], A1[q][2][3]), slope2);
                f[2 + q][1].p[0] = leaky2(pk_cvt(A1[q][1][0], A1[q][1][1]), slope2);
                f[2 + q][1].p[1] = leaky2(pk_cvt(A1[q][1][2], A1[q][1][3]), slope2);
                f[2 + q][1].p[2] = leaky2(pk_cvt(A1[q][3][0], A1[q][3][1]), slope2);
                f[2 + q][1].p[3] = leaky2(pk_cvt(A1[q][3][2], A1[q][3][3]), slope2);
            }
            // epi group 2
#pragma unroll
            for (int q = 0; q < 2; ++q) {
                f[4 + q][0].p[0] = leaky2(pk_cvt(A2[q][0][0], A2[q][0][1]), slope2);
                f[4 + q][0].p[1] = leaky2(pk_cvt(A2[q][0][2], A2[q][0][3]), slope2);
                f[4 + q][0].p[2] = leaky2(pk_cvt(A2[q][2][0], A2[q][2][1]), slope2);
                f[4 + q][0].p[3] = leaky2(pk_cvt(A2[q][2][2], A2[q][2][3]), slope2);
                f[4 + q][1].p[0] = leaky2(pk_cvt(A2[q][1][0], A2[q][1][1]), slope2);
                f[4 + q][1].p[1] = leaky2(pk_cvt(A2[q][1][2], A2[q][1][3]), slope2);
                f[4 + q][1].p[2] = leaky2(pk_cvt(A2[q][3][0], A2[q][3][1]), slope2);
                f[4 + q][1].p[3] = leaky2(pk_cvt(A2[q][3][2], A2[q][3][3]), slope2);
            }
            // peak acc liveness: 2 groups = 64 VGPRs (arch)

            wA0 = wA0n; wA1 = wA1n; bc0 = bc0n; bc1 = bc1n;
        }

        // ---- output layer: fdot2, then 4-group shuffle reduce ----
#pragma unroll
        for (int c = 0; c < NCHAIN; ++c)
#pragma unroll
            for (int nh = 0; nh < 2; ++nh) {
                float p = 0.0f;
#pragma unroll
                for (int jj = 0; jj < 4; ++jj)
                    p = __builtin_amdgcn_fdot2(f[c][nh].p[jj], wout2[jj], p, false);
                p += __shfl_xor(p, 16, 64);
                p += __shfl_xor(p, 32, 64);   // sum over all 4 k-groups
                float o = p + bo;
                int idx = it * (NCHAIN * 32) + c * 32 + 16 * nh + col;
                // 12 (c,nh) combos split 3-per-16-lane-group (coalesced 64B)
                if (((2 * c + nh) & 3) == g && idx < N) out[idx] = o;
            }

#pragma unroll
        for (int c = 0; c < NCHAIN; ++c) xc2[c] = xn2[c];
    }
}

extern "C" void kernel_launch(void* const* d_in, const int* in_sizes, int n_in,
                              void* d_out, int out_size, void* d_ws, size_t ws_size,
                              hipStream_t stream) {
    const float* x     = (const float*)d_in[0];
    const float* W_in  = (const float*)d_in[1];
    const float* b_in  = (const float*)d_in[2];
    const float* W_hid = (const float*)d_in[3];
    const float* b_hid = (const float*)d_in[4];
    const float* W_out = (const float*)d_in[5];
    const float* b_out = (const float*)d_in[6];
    float* out = (float*)d_out;

    int N = in_sizes[0];
    // 512 blocks x 4 waves = 2048 waves = 2 waves/SIMD (~150 arch VGPRs,
    // 0 AGPRs -> inside the 256 budget; 19.6 KiB LDS x 2 blocks/CU).
    // niter = ceil(N/192) = 5462 -> 2-3 iterations/wave.
    dim3 block(256);
    dim3 grid(512);
    mlp_mfma_kernel<<<grid, block, 0, stream>>>(x, W_in, b_in, W_hid, b_hid,
                                                W_out, b_out, out, N);
}

// Round 14
// 90.899 us; speedup vs baseline: 1.0790x; 1.0790x over previous
//
#include <hip/hip_runtime.h>

// Per-element MLP 1->32->(32x32)x9->1, leaky relu, v_mfma_f32_16x16x32_f16.
// R19 = R18's 8-waves/SIMD TLP probe with 512-thread blocks instead of 1024
// (R18 died twice on "container failed"; the only structural novelty vs
// every kernel that ran was the 1024-thread block -- hedge removes it while
// keeping the probe intact; R14 precedent: restructure-not-resubmit worked).
// Theory (unchanged): R17 falsified the AGPR-move explanation; corrected
// for gfx94x-formula fallback both pipes are <20% busy -> ~80% stall.
// ILP shape/micro-sched/unroll all null at 36-43us steady. Last axis:
// occupancy at 8 waves/SIMD. Per-wave busy ~12-15% -> 8 resident waves is
// exactly the needed coverage; a confirmed-occupancy null kills TLP and
// the session declares the ceiling.
// Wave <=64 VGPRs: NCHAIN=1 (32 elem/wave-iter), io-fragments in LDS,
// no rotation, rolled layer loop (R9 spill fix). Audit: f 8 + accs 16 +
// wA 8 + bc 8 + x 4 + addr ~12 ~= 56-64.
// launch_bounds(512,8): 8 waves/EU -> 64-reg cap, 4 blocks/CU; grid 1024;
// LDS 19.8 KiB x 4 = 79.2 KiB/CU. niter 32768 -> 4 iters/wave. N%32==0.
// Pass/fail: VGPR<=64 & WRITE~4MB (no spill); Occupancy 15.8 -> ~28-32%;
// steady 41.8 -> 15-22us if TLP cures; flat 40 => TLP null, ceiling.
#define NLAYERS 9
#define HID 32
#define SLOPE 0.01f

typedef _Float16 v2h __attribute__((ext_vector_type(2)));
typedef _Float16 v8h __attribute__((ext_vector_type(8)));
typedef float v4f __attribute__((ext_vector_type(4)));

union U8 { v8h v; v2h p[4]; };          // B-operand fragment (8 f16 = 4 VGPRs)

__device__ __forceinline__ v2h pk_cvt(float a, float b) {
    return __builtin_bit_cast(v2h, __builtin_amdgcn_cvt_pkrtz(a, b));
}
__device__ __forceinline__ v2h leaky2(v2h t, v2h s) {
    return __builtin_elementwise_max(t, t * s);
}
// k-slot (group g = lane>>4, elem j) -> logical hidden unit; derived from the
// verified 16x16 C/D layout so epilogue pk pairs feed the next B directly
// (validated numerically in R10/R14/R17).
__device__ __forceinline__ int umap(int g, int j) {
    return 4 * g + (j & 3) + 16 * (j >> 2);
}

__global__ __launch_bounds__(512, 8) void mlp_mfma_kernel(
    const float* __restrict__ x,
    const float* __restrict__ W_in,   // [1,32]
    const float* __restrict__ b_in,   // [32]
    const float* __restrict__ W_hid,  // [9,32,32]  W[l][k_in][n_out]
    const float* __restrict__ b_hid,  // [9,32]
    const float* __restrict__ W_out,  // [32,1]
    const float* __restrict__ b_out,  // [1]
    float* __restrict__ out, int N)
{
    // A-operand fragments, pre-permuted: lane ln=(i | g<<4) of tile t reads
    // 16B contiguous = W[umap(g,j)][16t+i], j=0..7. 64x16B = conflict-free.
    __shared__ __align__(16) _Float16 wA_sh[NLAYERS][2][64][8];  // 18 KiB
    // f32 bias in 16x16 C layout: tile t, entry 4g+r <- b_hid[16t+4g+r]
    __shared__ __align__(64) float bc_sh[NLAYERS][2][16];        // 1.1 KiB
    // io-layer fragments, indexed by k-group g (4 x b128 broadcast reads)
    __shared__ __align__(16) v2h win_sh[4][4], bin_sh[4][4], wout_sh[4][4];

    const int tid = threadIdx.x;
    for (int t = tid; t < NLAYERS * 2 * 64; t += blockDim.x) {
        int l = t >> 7, r = t & 127, tt = (r >> 6) & 1, ln = r & 63;
        int i = ln & 15, gg = ln >> 4;
        const float* Wl = W_hid + l * HID * HID;
        v8h w;
#pragma unroll
        for (int j = 0; j < 8; ++j)
            w[j] = (_Float16)Wl[umap(gg, j) * HID + 16 * tt + i];
        *(v8h*)&wA_sh[l][tt][ln][0] = w;
    }
    for (int t = tid; t < NLAYERS * HID; t += blockDim.x)
        ((float*)bc_sh)[t] = b_hid[t];   // flat layout matches b_hid exactly
    if (tid < 16) {
        int gg = tid >> 2, jj = tid & 3;
        int u0 = umap(gg, 2 * jj), u1 = umap(gg, 2 * jj + 1);  // u1 == u0+1
        win_sh[gg][jj]  = v2h{(_Float16)W_in[u0],  (_Float16)W_in[u1]};
        bin_sh[gg][jj]  = v2h{(_Float16)b_in[u0],  (_Float16)b_in[u1]};
        wout_sh[gg][jj] = v2h{(_Float16)W_out[u0], (_Float16)W_out[u1]};
    }
    __syncthreads();

    const int lane = tid & 63;
    const int g    = lane >> 4;     // k-group / C-row group
    const int col  = lane & 15;     // batch column within 16-wide half

    const float bo = b_out[0];
    const v2h slope2 = v2h{(_Float16)SLOPE, (_Float16)SLOPE};

    const int nwaves = (gridDim.x * blockDim.x) >> 6;
    const int wid    = ((blockIdx.x * blockDim.x) >> 6) + (tid >> 6);
    const int niter  = N >> 5;      // N % 32 == 0 (1M): no tail

    // ---- x prefetch for first iteration (2 cols per lane) ----
    v2h xc2 = v2h{(_Float16)0.f, (_Float16)0.f};
    if (wid < niter) {
        int i0 = wid * 32 + col;
        xc2 = pk_cvt(x[i0], x[i0 + 16]);
    }

    for (int it = wid; it < niter; it += nwaves) {
        // prefetch next iteration's x (hides HBM latency under compute)
        v2h xn2 = v2h{(_Float16)0.f, (_Float16)0.f};
        {
            int nit = it + nwaves;
            if (nit < niter) {
                int i0 = nit * 32 + col;
                xn2 = pk_cvt(x[i0], x[i0 + 16]);
            }
        }

        // ---- input layer: build B fragments for both halves ----
        U8 f0, f1;
        {
            const v2h* wi = &win_sh[g][0];
            const v2h* bi = &bin_sh[g][0];
#pragma unroll
            for (int jj = 0; jj < 4; ++jj) {
                v2h x20 = v2h{xc2[0], xc2[0]};
                v2h x21 = v2h{xc2[1], xc2[1]};
                f0.p[jj] = leaky2(x20 * wi[jj] + bi[jj], slope2);
                f1.p[jj] = leaky2(x21 * wi[jj] + bi[jj], slope2);
            }
        }

        // ---- 9 hidden layers: rolled loop, minimal state; layer-top lgkm
        // waits are covered by the 7 OTHER resident waves (the TLP probe).
#pragma unroll 1
        for (int l = 0; l < NLAYERS; ++l) {
            v8h wA0 = *(const v8h*)&wA_sh[l][0][lane][0];   // ds_read_b128
            v8h wA1 = *(const v8h*)&wA_sh[l][1][lane][0];   // ds_read_b128
            v4f bc0 = *(const v4f*)&bc_sh[l][0][4 * g];     // b128 broadcast
            v4f bc1 = *(const v4f*)&bc_sh[l][1][4 * g];

            v4f a00 = __builtin_amdgcn_mfma_f32_16x16x32_f16(wA0, f0.v, bc0, 0, 0, 0);
            v4f a01 = __builtin_amdgcn_mfma_f32_16x16x32_f16(wA0, f1.v, bc0, 0, 0, 0);
            v4f a10 = __builtin_amdgcn_mfma_f32_16x16x32_f16(wA1, f0.v, bc1, 0, 0, 0);
            v4f a11 = __builtin_amdgcn_mfma_f32_16x16x32_f16(wA1, f1.v, bc1, 0, 0, 0);

            f0.p[0] = leaky2(pk_cvt(a00[0], a00[1]), slope2);
            f0.p[1] = leaky2(pk_cvt(a00[2], a00[3]), slope2);
            f0.p[2] = leaky2(pk_cvt(a10[0], a10[1]), slope2);
            f0.p[3] = leaky2(pk_cvt(a10[2], a10[3]), slope2);
            f1.p[0] = leaky2(pk_cvt(a01[0], a01[1]), slope2);
            f1.p[1] = leaky2(pk_cvt(a01[2], a01[3]), slope2);
            f1.p[2] = leaky2(pk_cvt(a11[0], a11[1]), slope2);
            f1.p[3] = leaky2(pk_cvt(a11[2], a11[3]), slope2);
        }

        // ---- output layer: fdot2, 4-group shuffle reduce, store ----
        {
            const v2h* wo = &wout_sh[g][0];
            float p0 = 0.0f, p1 = 0.0f;
#pragma unroll
            for (int jj = 0; jj < 4; ++jj) {
                p0 = __builtin_amdgcn_fdot2(f0.p[jj], wo[jj], p0, false);
                p1 = __builtin_amdgcn_fdot2(f1.p[jj], wo[jj], p1, false);
            }
            p0 += __shfl_xor(p0, 16, 64);
            p0 += __shfl_xor(p0, 32, 64);   // sum over all 4 k-groups
            p1 += __shfl_xor(p1, 16, 64);
            p1 += __shfl_xor(p1, 32, 64);
            int idx = it * 32 + col;
            if (g == 0) out[idx]      = p0 + bo;   // half 0 by k-group 0
            if (g == 1) out[idx + 16] = p1 + bo;   // half 1 by k-group 1
        }

        xc2 = xn2;
    }
}

extern "C" void kernel_launch(void* const* d_in, const int* in_sizes, int n_in,
                              void* d_out, int out_size, void* d_ws, size_t ws_size,
                              hipStream_t stream) {
    const float* x     = (const float*)d_in[0];
    const float* W_in  = (const float*)d_in[1];
    const float* b_in  = (const float*)d_in[2];
    const float* W_hid = (const float*)d_in[3];
    const float* b_hid = (const float*)d_in[4];
    const float* W_out = (const float*)d_in[5];
    const float* b_out = (const float*)d_in[6];
    float* out = (float*)d_out;

    int N = in_sizes[0];
    // 1024 blocks x 8 waves = 8192 waves = 8 waves/SIMD (64-reg cap via
    // launch_bounds(512,8); 4 blocks/CU; LDS 19.8 KiB x 4 = 79.2 KiB/CU).
    // niter = N/32 = 32768 -> exactly 4 iterations/wave.
    dim3 block(512);
    dim3 grid(1024);
    mlp_mfma_kernel<<<grid, block, 0, stream>>>(x, W_in, b_in, W_hid, b_hid,
                                                W_out, b_out, out, N);
}